// Round 6
// baseline (145.861 us; speedup 1.0000x reference)
//
#include <hip/hip_runtime.h>
#include <math.h>

// Parzen window: out[n] = (1/H^32) * mean_m( all_d |test[n,d]-train[m,d]|/H <= 0.5 )
// H = 0.5  ->  inside iff |diff| <= 0.25 in every dim (exact in f32: both are
// power-of-2 scalings, no rounding mismatch vs reference's |d|/0.5 <= 0.5).
//
// Layout: block of 1024 threads = 16 waves. Each block owns 64 test points
// (lane l -> test point n = blockIdx.x*64 + l). Test point (32 f32) lives in
// registers (8x float4, compile-time indexed via full unroll). The 16 waves
// split M into chunks; within a chunk, m is WAVE-UNIFORM so the train-point
// load broadcasts to all 64 lanes, and __any(inside) gives a wave-coherent
// early exit over the 8 dim-groups (expected ~1 group checked for N(0,1) data).

__global__ __launch_bounds__(1024)
void parzen_kernel(const float* __restrict__ test_Xs,
                   const float* __restrict__ train_Xs,
                   float* __restrict__ out,
                   int M, float scale) {
    const int lane = threadIdx.x & 63;
    const int wave = threadIdx.x >> 6;         // 0..15
    const int n    = blockIdx.x * 64 + lane;   // this lane's test point

    // Load this lane's test point into registers.
    float4 t[8];
    const float4* tp = reinterpret_cast<const float4*>(test_Xs + (size_t)n * 32);
#pragma unroll
    for (int g = 0; g < 8; ++g) t[g] = tp[g];

    // This wave's m-range.
    const int chunk = (M + 15) / 16;
    const int m0 = wave * chunk;
    const int m1 = (m0 + chunk < M) ? (m0 + chunk) : M;

    int count = 0;
    for (int m = m0; m < m1; ++m) {
        const float4* xp = reinterpret_cast<const float4*>(train_Xs + (size_t)m * 32);
        bool in = true;
#pragma unroll
        for (int g = 0; g < 8; ++g) {
            const float4 x  = xp[g];       // wave-uniform address -> broadcast
            const float4 tg = t[g];
            bool c = (fabsf(tg.x - x.x) <= 0.25f) &
                     (fabsf(tg.y - x.y) <= 0.25f) &
                     (fabsf(tg.z - x.z) <= 0.25f) &
                     (fabsf(tg.w - x.w) <= 0.25f);
            in = in & c;
            if (!__any(in)) break;         // no lane alive -> skip rest of dims
        }
        count += in ? 1 : 0;               // after early break, in==false on all lanes
    }

    // Reduce the 16 waves' partial counts per test point.
    __shared__ int cnt[16][64];
    cnt[wave][lane] = count;
    __syncthreads();
    if (wave == 0) {
        int s = 0;
#pragma unroll
        for (int w = 0; w < 16; ++w) s += cnt[w][lane];
        out[n] = (float)s * scale;
    }
}

extern "C" void kernel_launch(void* const* d_in, const int* in_sizes, int n_in,
                              void* d_out, int out_size, void* d_ws, size_t ws_size,
                              hipStream_t stream) {
    const float* test_Xs  = (const float*)d_in[0];
    const float* train_Xs = (const float*)d_in[1];
    float* out = (float*)d_out;

    const int N = in_sizes[0] / 32;   // 1024
    const int M = in_sizes[1] / 32;   // 4096

    // coef/M = (1/0.5)^32 / M = 2^32 / M
    const float scale = (float)(4294967296.0 / (double)M);

    const int nBlocks = N / 64;       // 16 blocks x 1024 threads (16 waves each)
    parzen_kernel<<<nBlocks, 1024, 0, stream>>>(test_Xs, train_Xs, out, M, scale);
}

// Round 8
// 75.101 us; speedup vs baseline: 1.9422x; 1.9422x over previous
//
#include <hip/hip_runtime.h>
#include <math.h>

// Parzen window: out[n] = (1/H^32) * mean_m( all_d |test[n,d]-train[m,d]|/H <= 0.5 )
// H = 0.5 -> inside iff |diff| <= 0.25 every dim (exact: power-of-2 scalings).
//
// R6 lesson (rocprof): the __any-early-exit m-loop was LATENCY-bound
// (VALUBusy 2.4%, dur 105us) -- each iteration's load depended on the previous
// iteration's branch. Total brute-force VALU work is only ~3.5us chip-wide, so
// this version removes ALL branches from the inner loop and goes wide:
//   grid = 16 test-groups x 32 train-chunks = 512 blocks x 256 thr (2/CU).
//   lane (0..63) -> test point (32 f32 in regs); wave (0..3) -> 32-m slice of
//   the block's 128-m train chunk. Train loads are wave-uniform -> broadcast,
//   chunk (16KB) is L1-resident. No early exit: 8x-unrolled straight-line
//   sub/|cmp| per m, fully pipelinable.
// Cross-chunk reduction: one float atomicAdd per (block, test point). Exact:
// every addend is an integer multiple of scale=2^20, totals < 2^32 (<=12
// mantissa bits). out[] zeroed by init kernel on the same stream (d_out is
// re-poisoned to 0xAA before every timed call).

__global__ __launch_bounds__(256)
void parzen_init(float* __restrict__ out, int n) {
    int i = blockIdx.x * 256 + threadIdx.x;
    if (i < n) out[i] = 0.0f;
}

__global__ __launch_bounds__(256)
void parzen_main(const float* __restrict__ test_Xs,
                 const float* __restrict__ train_Xs,
                 float* __restrict__ out,
                 int M, int nchunk, int mchunk, float scale) {
    const int lane = threadIdx.x & 63;
    const int wave = threadIdx.x >> 6;            // 0..3
    const int g    = blockIdx.x / nchunk;         // test group (64 test pts)
    const int c    = blockIdx.x % nchunk;         // train chunk
    const int n    = g * 64 + lane;

    // This lane's test point -> 8x float4 in registers (compile-time indexed).
    float4 t[8];
    const float4* tp = reinterpret_cast<const float4*>(test_Xs + (size_t)n * 32);
#pragma unroll
    for (int q = 0; q < 8; ++q) t[q] = tp[q];

    // This wave's m-slice of the block's chunk.
    const int per_wave = mchunk >> 2;             // mchunk / 4 waves
    const int m0 = c * mchunk + wave * per_wave;
    const int m1 = (m0 + per_wave < M) ? (m0 + per_wave) : M;

    int count = 0;
    for (int m = m0; m < m1; ++m) {
        const float4* xp = reinterpret_cast<const float4*>(train_Xs + (size_t)m * 32);
        bool in = true;
#pragma unroll
        for (int q = 0; q < 8; ++q) {
            const float4 x  = xp[q];              // wave-uniform -> broadcast
            const float4 tg = t[q];
            in = in & (fabsf(tg.x - x.x) <= 0.25f)
                    & (fabsf(tg.y - x.y) <= 0.25f)
                    & (fabsf(tg.z - x.z) <= 0.25f)
                    & (fabsf(tg.w - x.w) <= 0.25f);
        }
        count += in ? 1 : 0;
    }

    // Reduce the block's 4 waves per test point, then one atomic per point.
    __shared__ int cnt[4][64];
    cnt[wave][lane] = count;
    __syncthreads();
    if (wave == 0) {
        int s = cnt[0][lane] + cnt[1][lane] + cnt[2][lane] + cnt[3][lane];
        if (s) atomicAdd(&out[n], (float)s * scale);  // skip if zero (common case)
    }
}

extern "C" void kernel_launch(void* const* d_in, const int* in_sizes, int n_in,
                              void* d_out, int out_size, void* d_ws, size_t ws_size,
                              hipStream_t stream) {
    const float* test_Xs  = (const float*)d_in[0];
    const float* train_Xs = (const float*)d_in[1];
    float* out = (float*)d_out;

    const int N = in_sizes[0] / 32;   // 1024
    const int M = in_sizes[1] / 32;   // 4096

    // coef/M = (1/0.5)^32 / M = 2^32 / M  (= 2^20 for M=4096)
    const float scale = (float)(4294967296.0 / (double)M);

    parzen_init<<<(out_size + 255) / 256, 256, 0, stream>>>(out, out_size);

    const int mchunk = 128;                       // 4 waves x 32 m each
    const int nchunk = (M + mchunk - 1) / mchunk; // 32
    const int ngroup = N / 64;                    // 16
    parzen_main<<<ngroup * nchunk, 256, 0, stream>>>(
        test_Xs, train_Xs, out, M, nchunk, mchunk, scale);
}